// Round 1
// 510.871 us; speedup vs baseline: 1.2286x; 1.2286x over previous
//
#include <hip/hip_runtime.h>

#define BLK 256

typedef float f4 __attribute__((ext_vector_type(4)));

// ---------------------------------------------------------------------------
// Kernel 1: per-feature sums. acc[f*14 + k]:
//   k=0..3  : sum_b x[b,f,k]
//   k=4..13 : sum_b x_i*x_j in tril order (00,10,11,20,21,22,30,31,32,33)
// Block = 64 features x 4 b-groups. Each thread accumulates its b-range with
// 8-deep unrolled loads (memory-level parallelism), then the 4 b-groups are
// LDS-reduced so only 1 atomicAdd per (f,k) per block hits memory.
// ---------------------------------------------------------------------------
#define ACCUM(v)                                              \
  do {                                                        \
    s0 += (v).x; s1 += (v).y; s2 += (v).z; s3 += (v).w;       \
    q00 += (v).x * (v).x;                                     \
    q10 += (v).y * (v).x; q11 += (v).y * (v).y;               \
    q20 += (v).z * (v).x; q21 += (v).z * (v).y;               \
    q22 += (v).z * (v).z;                                     \
    q30 += (v).w * (v).x; q31 += (v).w * (v).y;               \
    q32 += (v).w * (v).z; q33 += (v).w * (v).w;               \
  } while (0)

__global__ void qbn_stats(const float* __restrict__ x, float* __restrict__ acc,
                          int B, int F, int b_per) {
  const int fl = threadIdx.x & 63;   // feature within block (lane = feature)
  const int bg = threadIdx.x >> 6;   // b-group 0..3
  const int f = blockIdx.x * 64 + fl;

  float s0 = 0.f, s1 = 0.f, s2 = 0.f, s3 = 0.f;
  float q00 = 0.f, q10 = 0.f, q11 = 0.f, q20 = 0.f, q21 = 0.f;
  float q22 = 0.f, q30 = 0.f, q31 = 0.f, q32 = 0.f, q33 = 0.f;

  if (f < F) {
    int b0 = (blockIdx.y * 4 + bg) * b_per;
    int b1 = min(b0 + b_per, B);
    const float4* xv = (const float4*)x;
    int b = b0;
    // 8 independent loads in flight per iteration
    for (; b + 8 <= b1; b += 8) {
      float4 v0 = xv[(size_t)(b + 0) * F + f];
      float4 v1 = xv[(size_t)(b + 1) * F + f];
      float4 v2 = xv[(size_t)(b + 2) * F + f];
      float4 v3 = xv[(size_t)(b + 3) * F + f];
      float4 v4 = xv[(size_t)(b + 4) * F + f];
      float4 v5 = xv[(size_t)(b + 5) * F + f];
      float4 v6 = xv[(size_t)(b + 6) * F + f];
      float4 v7 = xv[(size_t)(b + 7) * F + f];
      ACCUM(v0); ACCUM(v1); ACCUM(v2); ACCUM(v3);
      ACCUM(v4); ACCUM(v5); ACCUM(v6); ACCUM(v7);
    }
    for (; b < b1; ++b) {
      float4 v = xv[(size_t)b * F + f];
      ACCUM(v);
    }
  }

  __shared__ float red[4][64][14];
  {
    float* r = &red[bg][fl][0];
    r[0] = s0;  r[1] = s1;  r[2] = s2;  r[3] = s3;
    r[4] = q00; r[5] = q10; r[6] = q11; r[7] = q20; r[8] = q21;
    r[9] = q22; r[10] = q30; r[11] = q31; r[12] = q32; r[13] = q33;
  }
  __syncthreads();
  if (bg == 0 && f < F) {
    float* a = acc + (size_t)f * 14;
#pragma unroll
    for (int k = 0; k < 14; ++k) {
      float t = red[0][fl][k] + red[1][fl][k] + red[2][fl][k] + red[3][fl][k];
      atomicAdd(a + k, t);
    }
  }
}

// ---------------------------------------------------------------------------
// Cholesky of (cov + eps*I). Returns false if any pivot is non-positive / NaN
// (the condition under which jnp.linalg.cholesky yields NaN).
// ---------------------------------------------------------------------------
__device__ __forceinline__ bool cholesky4(const float cov[4][4], float eps,
                                          float L[4][4]) {
  float A[4][4];
#pragma unroll
  for (int i = 0; i < 4; ++i)
#pragma unroll
    for (int j = 0; j < 4; ++j) A[i][j] = cov[i][j];
#pragma unroll
  for (int i = 0; i < 4; ++i) A[i][i] += eps;

#pragma unroll
  for (int j = 0; j < 4; ++j) {
    float d = A[j][j];
#pragma unroll
    for (int k = 0; k < 4; ++k)
      if (k < j) d -= L[j][k] * L[j][k];
    if (!(d > 0.0f)) return false;  // catches d<=0 and NaN
    float s = sqrtf(d);
    L[j][j] = s;
    float inv = 1.0f / s;
#pragma unroll
    for (int i = 0; i < 4; ++i) {
      if (i > j) {
        float v = A[i][j];
#pragma unroll
        for (int k = 0; k < 4; ++k)
          if (k < j) v -= L[i][k] * L[j][k];
        L[i][j] = v * inv;
      } else if (i < j) {
        L[i][j] = 0.0f;
      }
    }
  }
  return true;
}

// ---------------------------------------------------------------------------
// Kernel 2: per-feature finalize. Produces Ac[f*20]: A (4x4 row-major) then c,
// where out = A @ x + c  with  A = gamma_sym @ L^-1,  c = beta - A @ mean.
// ---------------------------------------------------------------------------
__global__ void qbn_finalize(const float* __restrict__ acc,
                             const float* __restrict__ gamma,
                             const float* __restrict__ beta,
                             float* __restrict__ Ac, int B, int F) {
  int f = blockIdx.x * blockDim.x + threadIdx.x;
  if (f >= F) return;
  const float* a = acc + (size_t)f * 14;
  float invB = 1.0f / (float)B;
  float m[4] = {a[0] * invB, a[1] * invB, a[2] * invB, a[3] * invB};

  float cov[4][4];
  cov[0][0] = a[4] * invB - m[0] * m[0];
  cov[1][0] = a[5] * invB - m[1] * m[0];
  cov[1][1] = a[6] * invB - m[1] * m[1];
  cov[2][0] = a[7] * invB - m[2] * m[0];
  cov[2][1] = a[8] * invB - m[2] * m[1];
  cov[2][2] = a[9] * invB - m[2] * m[2];
  cov[3][0] = a[10] * invB - m[3] * m[0];
  cov[3][1] = a[11] * invB - m[3] * m[1];
  cov[3][2] = a[12] * invB - m[3] * m[2];
  cov[3][3] = a[13] * invB - m[3] * m[3];
  cov[0][1] = cov[1][0]; cov[0][2] = cov[2][0]; cov[0][3] = cov[3][0];
  cov[1][2] = cov[2][1]; cov[1][3] = cov[3][1]; cov[2][3] = cov[3][2];

  // 3-level fallback exactly as reference
  float L[4][4];
  if (!cholesky4(cov, 1e-5f, L)) {
    if (!cholesky4(cov, 0.1f, L)) {
      float dm = 0.25f * (fabsf(cov[0][0]) + fabsf(cov[1][1]) +
                          fabsf(cov[2][2]) + fabsf(cov[3][3]));
      float scale = sqrtf(fmaxf(dm, 1.0f));
#pragma unroll
      for (int i = 0; i < 4; ++i)
#pragma unroll
        for (int j = 0; j < 4; ++j) L[i][j] = (i == j) ? scale : 0.0f;
    }
  }

  // Invert lower-triangular L (forward substitution vs identity)
  float Li[4][4];
#pragma unroll
  for (int i = 0; i < 4; ++i)
#pragma unroll
    for (int j = 0; j < 4; ++j) Li[i][j] = 0.0f;
#pragma unroll
  for (int j = 0; j < 4; ++j) {
    Li[j][j] = 1.0f / L[j][j];
#pragma unroll
    for (int i = 0; i < 4; ++i) {
      if (i > j) {
        float s = 0.0f;
#pragma unroll
        for (int k = 0; k < 4; ++k)
          if (k >= j && k < i) s += L[i][k] * Li[k][j];
        Li[i][j] = -s / L[i][i];
      }
    }
  }

  // gamma_sym from tril order (0,0),(1,0),(1,1),(2,0),(2,1),(2,2),(3,0),(3,1),(3,2),(3,3)
  const float* g = gamma + (size_t)f * 10;
  float G[4][4];
  G[0][0] = g[0];
  G[1][0] = g[1]; G[0][1] = g[1];
  G[1][1] = g[2];
  G[2][0] = g[3]; G[0][2] = g[3];
  G[2][1] = g[4]; G[1][2] = g[4];
  G[2][2] = g[5];
  G[3][0] = g[6]; G[0][3] = g[6];
  G[3][1] = g[7]; G[1][3] = g[7];
  G[3][2] = g[8]; G[2][3] = g[8];
  G[3][3] = g[9];

  // A = G @ Li
  float A[4][4];
#pragma unroll
  for (int i = 0; i < 4; ++i)
#pragma unroll
    for (int j = 0; j < 4; ++j) {
      float s = 0.0f;
#pragma unroll
      for (int k = 0; k < 4; ++k) s += G[i][k] * Li[k][j];
      A[i][j] = s;
    }

  const float* bt = beta + (size_t)f * 4;
  float c[4];
#pragma unroll
  for (int i = 0; i < 4; ++i)
    c[i] = bt[i] - (A[i][0] * m[0] + A[i][1] * m[1] + A[i][2] * m[2] + A[i][3] * m[3]);

  float* o = Ac + (size_t)f * 20;
#pragma unroll
  for (int i = 0; i < 4; ++i)
#pragma unroll
    for (int j = 0; j < 4; ++j) o[i * 4 + j] = A[i][j];
#pragma unroll
  for (int i = 0; i < 4; ++i) o[16 + i] = c[i];
}

// ---------------------------------------------------------------------------
// Kernel 3: out[b,f,:] = A[f] @ x[b,f,:] + c[f]
// Unrolled x4 for in-flight loads; nontemporal stores so `out` doesn't evict
// the L3-resident x that this kernel is re-reading.
// ---------------------------------------------------------------------------
__device__ __forceinline__ float4 qbn_xform(float4 v, float4 A0, float4 A1,
                                            float4 A2, float4 A3, float4 C) {
  float4 o;
  o.x = A0.x * v.x + A0.y * v.y + A0.z * v.z + A0.w * v.w + C.x;
  o.y = A1.x * v.x + A1.y * v.y + A1.z * v.z + A1.w * v.w + C.y;
  o.z = A2.x * v.x + A2.y * v.y + A2.z * v.z + A2.w * v.w + C.z;
  o.w = A3.x * v.x + A3.y * v.y + A3.z * v.z + A3.w * v.w + C.w;
  return o;
}

__global__ void qbn_apply(const float* __restrict__ x,
                          const float* __restrict__ Ac,
                          float* __restrict__ out, int B, int F, int b_per) {
  int f = blockIdx.x * blockDim.x + threadIdx.x;
  if (f >= F) return;
  const float4* p = (const float4*)(Ac + (size_t)f * 20);  // 80B stride, 16B aligned
  float4 A0 = p[0], A1 = p[1], A2 = p[2], A3 = p[3], C = p[4];

  int b0 = blockIdx.y * b_per;
  int b1 = min(b0 + b_per, B);
  const float4* xv = (const float4*)x;
  float4* ov = (float4*)out;
  int b = b0;
  for (; b + 4 <= b1; b += 4) {
    size_t i0 = (size_t)(b + 0) * F + f;
    size_t i1 = (size_t)(b + 1) * F + f;
    size_t i2 = (size_t)(b + 2) * F + f;
    size_t i3 = (size_t)(b + 3) * F + f;
    float4 v0 = xv[i0];
    float4 v1 = xv[i1];
    float4 v2 = xv[i2];
    float4 v3 = xv[i3];
    float4 o0 = qbn_xform(v0, A0, A1, A2, A3, C);
    float4 o1 = qbn_xform(v1, A0, A1, A2, A3, C);
    float4 o2 = qbn_xform(v2, A0, A1, A2, A3, C);
    float4 o3 = qbn_xform(v3, A0, A1, A2, A3, C);
    __builtin_nontemporal_store(*(const f4*)&o0, (f4*)(ov + i0));
    __builtin_nontemporal_store(*(const f4*)&o1, (f4*)(ov + i1));
    __builtin_nontemporal_store(*(const f4*)&o2, (f4*)(ov + i2));
    __builtin_nontemporal_store(*(const f4*)&o3, (f4*)(ov + i3));
  }
  for (; b < b1; ++b) {
    size_t idx = (size_t)b * F + f;
    float4 v = xv[idx];
    float4 o = qbn_xform(v, A0, A1, A2, A3, C);
    __builtin_nontemporal_store(*(const f4*)&o, (f4*)(ov + idx));
  }
}

extern "C" void kernel_launch(void* const* d_in, const int* in_sizes, int n_in,
                              void* d_out, int out_size, void* d_ws, size_t ws_size,
                              hipStream_t stream) {
  const float* x = (const float*)d_in[0];
  const float* gamma = (const float*)d_in[1];
  const float* beta = (const float*)d_in[2];
  float* out = (float*)d_out;

  int F = in_sizes[2] / 4;                 // beta is [F,4]
  int B = in_sizes[0] / (F * 4);           // x is [B,F,4]

  float* acc = (float*)d_ws;               // F*14 floats
  float* Ac = acc + (size_t)F * 14;        // F*20 floats (byte offset F*56, 16B-aligned for F mult of 8)

  hipMemsetAsync(d_ws, 0, (size_t)F * 14 * sizeof(float), stream);

  // Stats: 64 features/block x 4 b-groups, grid (F/64, SNBY) = 1024 blocks
  int fblocks64 = (F + 63) / 64;           // 32
  const int SNBY = 32;
  int sb_per = (B + SNBY * 4 - 1) / (SNBY * 4);  // 64
  qbn_stats<<<dim3(fblocks64, SNBY), 256, 0, stream>>>(x, acc, B, F, sb_per);

  int fblocks = (F + BLK - 1) / BLK;       // 8
  qbn_finalize<<<fblocks, BLK, 0, stream>>>(acc, gamma, beta, Ac, B, F);

  // Apply: grid (8, 256) = 2048 blocks -> full occupancy, x4 unrolled
  const int ANBY = 256;
  int ab_per = (B + ANBY - 1) / ANBY;      // 32
  qbn_apply<<<dim3(fblocks, ANBY), BLK, 0, stream>>>(x, Ac, out, B, F, ab_per);
}

// Round 2
// 498.856 us; speedup vs baseline: 1.2582x; 1.0241x over previous
//
#include <hip/hip_runtime.h>

#define BLK 256

typedef float f4 __attribute__((ext_vector_type(4)));

// ---------------------------------------------------------------------------
// Stats accumulation macro: 4 sums + 10 tril second moments per float4.
// ---------------------------------------------------------------------------
#define ACCUM(v)                                              \
  do {                                                        \
    s0 += (v).x; s1 += (v).y; s2 += (v).z; s3 += (v).w;       \
    q00 += (v).x * (v).x;                                     \
    q10 += (v).y * (v).x; q11 += (v).y * (v).y;               \
    q20 += (v).z * (v).x; q21 += (v).z * (v).y;               \
    q22 += (v).z * (v).z;                                     \
    q30 += (v).w * (v).x; q31 += (v).w * (v).y;               \
    q32 += (v).w * (v).z; q33 += (v).w * (v).w;               \
  } while (0)

#define ACCUM_BODY(OUT_STMT)                                                \
  const int fl = threadIdx.x & 63;   /* feature within block */             \
  const int bg = threadIdx.x >> 6;   /* b-group 0..3 */                     \
  const int f = blockIdx.x * 64 + fl;                                       \
  float s0 = 0.f, s1 = 0.f, s2 = 0.f, s3 = 0.f;                             \
  float q00 = 0.f, q10 = 0.f, q11 = 0.f, q20 = 0.f, q21 = 0.f;              \
  float q22 = 0.f, q30 = 0.f, q31 = 0.f, q32 = 0.f, q33 = 0.f;              \
  if (f < F) {                                                              \
    int b0 = (blockIdx.y * 4 + bg) * b_per;                                 \
    int b1 = min(b0 + b_per, B);                                            \
    const float4* xv = (const float4*)x;                                    \
    int b = b0;                                                             \
    for (; b + 8 <= b1; b += 8) {                                           \
      size_t base = (size_t)b * F + f;                                      \
      float4 v0 = xv[base + 0 * (size_t)F];                                 \
      float4 v1 = xv[base + 1 * (size_t)F];                                 \
      float4 v2 = xv[base + 2 * (size_t)F];                                 \
      float4 v3 = xv[base + 3 * (size_t)F];                                 \
      float4 v4 = xv[base + 4 * (size_t)F];                                 \
      float4 v5 = xv[base + 5 * (size_t)F];                                 \
      float4 v6 = xv[base + 6 * (size_t)F];                                 \
      float4 v7 = xv[base + 7 * (size_t)F];                                 \
      ACCUM(v0); ACCUM(v1); ACCUM(v2); ACCUM(v3);                           \
      ACCUM(v4); ACCUM(v5); ACCUM(v6); ACCUM(v7);                           \
    }                                                                       \
    for (; b < b1; ++b) {                                                   \
      float4 v = xv[(size_t)b * F + f];                                     \
      ACCUM(v);                                                             \
    }                                                                       \
  }                                                                         \
  __shared__ float red[4][64][14];                                          \
  {                                                                         \
    float* r = &red[bg][fl][0];                                             \
    r[0] = s0;  r[1] = s1;  r[2] = s2;  r[3] = s3;                          \
    r[4] = q00; r[5] = q10; r[6] = q11; r[7] = q20; r[8] = q21;             \
    r[9] = q22; r[10] = q30; r[11] = q31; r[12] = q32; r[13] = q33;         \
  }                                                                         \
  __syncthreads();                                                          \
  if (bg == 0 && f < F) {                                                   \
    float t[14];                                                            \
    _Pragma("unroll")                                                       \
    for (int k = 0; k < 14; ++k)                                            \
      t[k] = red[0][fl][k] + red[1][fl][k] + red[2][fl][k] + red[3][fl][k]; \
    OUT_STMT                                                                \
  }

// ---------------------------------------------------------------------------
// Kernel 1a (preferred): per-feature partial sums, race-free. Each y-block
// writes its own 16-float slot: part[(y*F + f)*16 + k]. No atomics, no memset.
// ---------------------------------------------------------------------------
__global__ void qbn_stats_part(const float* __restrict__ x,
                               float* __restrict__ part,
                               int B, int F, int b_per) {
  ACCUM_BODY({
    float4* p = (float4*)(part + ((size_t)blockIdx.y * F + f) * 16);
    p[0] = make_float4(t[0], t[1], t[2], t[3]);
    p[1] = make_float4(t[4], t[5], t[6], t[7]);
    p[2] = make_float4(t[8], t[9], t[10], t[11]);
    p[3] = make_float4(t[12], t[13], 0.f, 0.f);
  })
}

// ---------------------------------------------------------------------------
// Kernel 1b (fallback, small ws): atomic accumulation into acc[f*14 + k].
// ---------------------------------------------------------------------------
__global__ void qbn_stats_atomic(const float* __restrict__ x,
                                 float* __restrict__ acc,
                                 int B, int F, int b_per) {
  ACCUM_BODY({
    float* a = acc + (size_t)f * 14;
    _Pragma("unroll")
    for (int k = 0; k < 14; ++k) atomicAdd(a + k, t[k]);
  })
}

// ---------------------------------------------------------------------------
// Cholesky of (cov + eps*I). Returns false if any pivot is non-positive / NaN
// (the condition under which jnp.linalg.cholesky yields NaN).
// ---------------------------------------------------------------------------
__device__ __forceinline__ bool cholesky4(const float cov[4][4], float eps,
                                          float L[4][4]) {
  float A[4][4];
#pragma unroll
  for (int i = 0; i < 4; ++i)
#pragma unroll
    for (int j = 0; j < 4; ++j) A[i][j] = cov[i][j];
#pragma unroll
  for (int i = 0; i < 4; ++i) A[i][i] += eps;

#pragma unroll
  for (int j = 0; j < 4; ++j) {
    float d = A[j][j];
#pragma unroll
    for (int k = 0; k < 4; ++k)
      if (k < j) d -= L[j][k] * L[j][k];
    if (!(d > 0.0f)) return false;  // catches d<=0 and NaN
    float s = sqrtf(d);
    L[j][j] = s;
    float inv = 1.0f / s;
#pragma unroll
    for (int i = 0; i < 4; ++i) {
      if (i > j) {
        float v = A[i][j];
#pragma unroll
        for (int k = 0; k < 4; ++k)
          if (k < j) v -= L[i][k] * L[j][k];
        L[i][j] = v * inv;
      } else if (i < j) {
        L[i][j] = 0.0f;
      }
    }
  }
  return true;
}

// ---------------------------------------------------------------------------
// Shared finalize math: from 14 sums -> A (4x4) and c (4), written to Ac[f*20].
// ---------------------------------------------------------------------------
__device__ __forceinline__ void finalize_feature(const float a[14],
                                                 const float* __restrict__ gamma,
                                                 const float* __restrict__ beta,
                                                 float* __restrict__ Ac,
                                                 int B, int F, int f) {
  float invB = 1.0f / (float)B;
  float m[4] = {a[0] * invB, a[1] * invB, a[2] * invB, a[3] * invB};

  float cov[4][4];
  cov[0][0] = a[4] * invB - m[0] * m[0];
  cov[1][0] = a[5] * invB - m[1] * m[0];
  cov[1][1] = a[6] * invB - m[1] * m[1];
  cov[2][0] = a[7] * invB - m[2] * m[0];
  cov[2][1] = a[8] * invB - m[2] * m[1];
  cov[2][2] = a[9] * invB - m[2] * m[2];
  cov[3][0] = a[10] * invB - m[3] * m[0];
  cov[3][1] = a[11] * invB - m[3] * m[1];
  cov[3][2] = a[12] * invB - m[3] * m[2];
  cov[3][3] = a[13] * invB - m[3] * m[3];
  cov[0][1] = cov[1][0]; cov[0][2] = cov[2][0]; cov[0][3] = cov[3][0];
  cov[1][2] = cov[2][1]; cov[1][3] = cov[3][1]; cov[2][3] = cov[3][2];

  // 3-level fallback exactly as reference
  float L[4][4];
  if (!cholesky4(cov, 1e-5f, L)) {
    if (!cholesky4(cov, 0.1f, L)) {
      float dm = 0.25f * (fabsf(cov[0][0]) + fabsf(cov[1][1]) +
                          fabsf(cov[2][2]) + fabsf(cov[3][3]));
      float scale = sqrtf(fmaxf(dm, 1.0f));
#pragma unroll
      for (int i = 0; i < 4; ++i)
#pragma unroll
        for (int j = 0; j < 4; ++j) L[i][j] = (i == j) ? scale : 0.0f;
    }
  }

  // Invert lower-triangular L (forward substitution vs identity)
  float Li[4][4];
#pragma unroll
  for (int i = 0; i < 4; ++i)
#pragma unroll
    for (int j = 0; j < 4; ++j) Li[i][j] = 0.0f;
#pragma unroll
  for (int j = 0; j < 4; ++j) {
    Li[j][j] = 1.0f / L[j][j];
#pragma unroll
    for (int i = 0; i < 4; ++i) {
      if (i > j) {
        float s = 0.0f;
#pragma unroll
        for (int k = 0; k < 4; ++k)
          if (k >= j && k < i) s += L[i][k] * Li[k][j];
        Li[i][j] = -s / L[i][i];
      }
    }
  }

  // gamma_sym from tril order (0,0),(1,0),(1,1),(2,0),(2,1),(2,2),(3,0),(3,1),(3,2),(3,3)
  const float* g = gamma + (size_t)f * 10;
  float G[4][4];
  G[0][0] = g[0];
  G[1][0] = g[1]; G[0][1] = g[1];
  G[1][1] = g[2];
  G[2][0] = g[3]; G[0][2] = g[3];
  G[2][1] = g[4]; G[1][2] = g[4];
  G[2][2] = g[5];
  G[3][0] = g[6]; G[0][3] = g[6];
  G[3][1] = g[7]; G[1][3] = g[7];
  G[3][2] = g[8]; G[2][3] = g[8];
  G[3][3] = g[9];

  // A = G @ Li
  float A[4][4];
#pragma unroll
  for (int i = 0; i < 4; ++i)
#pragma unroll
    for (int j = 0; j < 4; ++j) {
      float s = 0.0f;
#pragma unroll
      for (int k = 0; k < 4; ++k) s += G[i][k] * Li[k][j];
      A[i][j] = s;
    }

  const float* bt = beta + (size_t)f * 4;
  float c[4];
#pragma unroll
  for (int i = 0; i < 4; ++i)
    c[i] = bt[i] - (A[i][0] * m[0] + A[i][1] * m[1] + A[i][2] * m[2] + A[i][3] * m[3]);

  float* o = Ac + (size_t)f * 20;
#pragma unroll
  for (int i = 0; i < 4; ++i)
#pragma unroll
    for (int j = 0; j < 4; ++j) o[i * 4 + j] = A[i][j];
#pragma unroll
  for (int i = 0; i < 4; ++i) o[16 + i] = c[i];
}

// ---------------------------------------------------------------------------
// Kernel 2a: finalize from NY race-free partials (16-float stride each).
// ---------------------------------------------------------------------------
__global__ void qbn_finalize_part(const float* __restrict__ part,
                                  const float* __restrict__ gamma,
                                  const float* __restrict__ beta,
                                  float* __restrict__ Ac, int B, int F, int NY) {
  int f = blockIdx.x * blockDim.x + threadIdx.x;
  if (f >= F) return;
  float a[14];
#pragma unroll
  for (int k = 0; k < 14; ++k) a[k] = 0.f;
  for (int y = 0; y < NY; ++y) {
    const float4* p = (const float4*)(part + ((size_t)y * F + f) * 16);
    float4 p0 = p[0], p1 = p[1], p2 = p[2], p3 = p[3];
    a[0] += p0.x;  a[1] += p0.y;  a[2] += p0.z;  a[3] += p0.w;
    a[4] += p1.x;  a[5] += p1.y;  a[6] += p1.z;  a[7] += p1.w;
    a[8] += p2.x;  a[9] += p2.y;  a[10] += p2.z; a[11] += p2.w;
    a[12] += p3.x; a[13] += p3.y;
  }
  finalize_feature(a, gamma, beta, Ac, B, F, f);
}

// ---------------------------------------------------------------------------
// Kernel 2b: finalize from atomic accumulator acc[f*14 + k].
// ---------------------------------------------------------------------------
__global__ void qbn_finalize_atomic(const float* __restrict__ acc,
                                    const float* __restrict__ gamma,
                                    const float* __restrict__ beta,
                                    float* __restrict__ Ac, int B, int F) {
  int f = blockIdx.x * blockDim.x + threadIdx.x;
  if (f >= F) return;
  const float* ap = acc + (size_t)f * 14;
  float a[14];
#pragma unroll
  for (int k = 0; k < 14; ++k) a[k] = ap[k];
  finalize_feature(a, gamma, beta, Ac, B, F, f);
}

// ---------------------------------------------------------------------------
// Kernel 3: out[b,f,:] = A[f] @ x[b,f,:] + c[f]
// 8-deep unrolled loads for MLP; nontemporal stores so `out` doesn't evict
// the L3-resident x that this kernel is re-reading.
// ---------------------------------------------------------------------------
__device__ __forceinline__ float4 qbn_xform(float4 v, float4 A0, float4 A1,
                                            float4 A2, float4 A3, float4 C) {
  float4 o;
  o.x = A0.x * v.x + A0.y * v.y + A0.z * v.z + A0.w * v.w + C.x;
  o.y = A1.x * v.x + A1.y * v.y + A1.z * v.z + A1.w * v.w + C.y;
  o.z = A2.x * v.x + A2.y * v.y + A2.z * v.z + A2.w * v.w + C.z;
  o.w = A3.x * v.x + A3.y * v.y + A3.z * v.z + A3.w * v.w + C.w;
  return o;
}

__global__ void qbn_apply(const float* __restrict__ x,
                          const float* __restrict__ Ac,
                          float* __restrict__ out, int B, int F, int b_per) {
  int f = blockIdx.x * blockDim.x + threadIdx.x;
  if (f >= F) return;
  const float4* p = (const float4*)(Ac + (size_t)f * 20);  // 80B stride, 16B aligned
  float4 A0 = p[0], A1 = p[1], A2 = p[2], A3 = p[3], C = p[4];

  int b0 = blockIdx.y * b_per;
  int b1 = min(b0 + b_per, B);
  const float4* xv = (const float4*)x;
  float4* ov = (float4*)out;
  int b = b0;
  for (; b + 8 <= b1; b += 8) {
    size_t base = (size_t)b * F + f;
    float4 v0 = xv[base + 0 * (size_t)F];
    float4 v1 = xv[base + 1 * (size_t)F];
    float4 v2 = xv[base + 2 * (size_t)F];
    float4 v3 = xv[base + 3 * (size_t)F];
    float4 v4 = xv[base + 4 * (size_t)F];
    float4 v5 = xv[base + 5 * (size_t)F];
    float4 v6 = xv[base + 6 * (size_t)F];
    float4 v7 = xv[base + 7 * (size_t)F];
    float4 o0 = qbn_xform(v0, A0, A1, A2, A3, C);
    float4 o1 = qbn_xform(v1, A0, A1, A2, A3, C);
    float4 o2 = qbn_xform(v2, A0, A1, A2, A3, C);
    float4 o3 = qbn_xform(v3, A0, A1, A2, A3, C);
    float4 o4 = qbn_xform(v4, A0, A1, A2, A3, C);
    float4 o5 = qbn_xform(v5, A0, A1, A2, A3, C);
    float4 o6 = qbn_xform(v6, A0, A1, A2, A3, C);
    float4 o7 = qbn_xform(v7, A0, A1, A2, A3, C);
    __builtin_nontemporal_store(*(const f4*)&o0, (f4*)(ov + base + 0 * (size_t)F));
    __builtin_nontemporal_store(*(const f4*)&o1, (f4*)(ov + base + 1 * (size_t)F));
    __builtin_nontemporal_store(*(const f4*)&o2, (f4*)(ov + base + 2 * (size_t)F));
    __builtin_nontemporal_store(*(const f4*)&o3, (f4*)(ov + base + 3 * (size_t)F));
    __builtin_nontemporal_store(*(const f4*)&o4, (f4*)(ov + base + 4 * (size_t)F));
    __builtin_nontemporal_store(*(const f4*)&o5, (f4*)(ov + base + 5 * (size_t)F));
    __builtin_nontemporal_store(*(const f4*)&o6, (f4*)(ov + base + 6 * (size_t)F));
    __builtin_nontemporal_store(*(const f4*)&o7, (f4*)(ov + base + 7 * (size_t)F));
  }
  for (; b < b1; ++b) {
    size_t idx = (size_t)b * F + f;
    float4 v = xv[idx];
    float4 o = qbn_xform(v, A0, A1, A2, A3, C);
    __builtin_nontemporal_store(*(const f4*)&o, (f4*)(ov + idx));
  }
}

extern "C" void kernel_launch(void* const* d_in, const int* in_sizes, int n_in,
                              void* d_out, int out_size, void* d_ws, size_t ws_size,
                              hipStream_t stream) {
  const float* x = (const float*)d_in[0];
  const float* gamma = (const float*)d_in[1];
  const float* beta = (const float*)d_in[2];
  float* out = (float*)d_out;

  int F = in_sizes[2] / 4;                 // beta is [F,4]
  int B = in_sizes[0] / (F * 4);           // x is [B,F,4]

  int fblocks64 = (F + 63) / 64;           // 32
  int fblocks = (F + BLK - 1) / BLK;       // 8

  const int NY = 64;                       // stats y-blocks (partials path)
  size_t part_floats = (size_t)NY * F * 16;
  size_t need_part = (part_floats + (size_t)F * 20) * sizeof(float);

  if (ws_size >= need_part) {
    // --- Race-free partials path: no atomics, no memset ---
    float* part = (float*)d_ws;                      // NY*F*16 floats
    float* Ac = part + part_floats;                  // F*20 floats
    int sb_per = (B + NY * 4 - 1) / (NY * 4);        // 32
    qbn_stats_part<<<dim3(fblocks64, NY), 256, 0, stream>>>(x, part, B, F, sb_per);
    qbn_finalize_part<<<fblocks, BLK, 0, stream>>>(part, gamma, beta, Ac, B, F, NY);
    const int ANBY = 256;
    int ab_per = (B + ANBY - 1) / ANBY;              // 32
    qbn_apply<<<dim3(fblocks, ANBY), BLK, 0, stream>>>(x, Ac, out, B, F, ab_per);
  } else {
    // --- Fallback: atomic accumulation (small workspace) ---
    float* acc = (float*)d_ws;                       // F*14 floats
    float* Ac = acc + (size_t)F * 14;                // F*20 floats
    hipMemsetAsync(d_ws, 0, (size_t)F * 14 * sizeof(float), stream);
    const int SNBY = 32;
    int sb_per = (B + SNBY * 4 - 1) / (SNBY * 4);
    qbn_stats_atomic<<<dim3(fblocks64, SNBY), 256, 0, stream>>>(x, acc, B, F, sb_per);
    qbn_finalize_atomic<<<fblocks, BLK, 0, stream>>>(acc, gamma, beta, Ac, B, F);
    const int ANBY = 256;
    int ab_per = (B + ANBY - 1) / ANBY;
    qbn_apply<<<dim3(fblocks, ANBY), BLK, 0, stream>>>(x, Ac, out, B, F, ab_per);
  }
}